// Round 12
// baseline (257.648 us; speedup 1.0000x reference)
//
#include <hip/hip_runtime.h>
#include <hip/hip_bf16.h>
#include <math.h>

#define D_MODEL 512
#define D_FF    2048
#define NE      8
#define T_TOK   8192
#define SLABU   (16384 * 64)   // ushorts per 64-col K-slab of H

typedef __attribute__((ext_vector_type(8))) short bf16x8;
typedef __attribute__((ext_vector_type(4))) float f32x4;

static __device__ __forceinline__ unsigned short f2bf(float f){
    union { float f; unsigned u; } v; v.f = f;
    unsigned r = v.u + 0x7FFFu + ((v.u >> 16) & 1u);   // RNE
    return (unsigned short)(r >> 16);
}
static __device__ __forceinline__ float bf2f(unsigned short u){
    union { unsigned u; float f; } v; v.u = ((unsigned)u) << 16; return v.f;
}

// tanh-form GELU via exp2 (abs err <= ~3e-4, well under bf16 rounding of h)
static __device__ __forceinline__ float gelu_f(float x){
    float z = 0.7978845608028654f * (x + 0.044715f * x * x * x);
    float e = __builtin_amdgcn_exp2f(z * 2.8853900817779268f);  // e^(2z)
    float t = 1.f - 2.f * __builtin_amdgcn_rcpf(e + 1.f);       // tanh(z)
    return 0.5f * x * (1.f + t);
}

static __device__ __forceinline__ void gload16(const void* g, void* l){
    __builtin_amdgcn_global_load_lds((const __attribute__((address_space(1))) unsigned int*)g,
                                     (__attribute__((address_space(3))) unsigned int*)l, 16, 0, 0);
}

// ---------------- f32 -> bf16 conversion of BOTH weight tensors in one dispatch ----------------
__global__ __launch_bounds__(256) void cvt2_f32_bf16(const float* __restrict__ s1,
                                                     unsigned short* __restrict__ d1,
                                                     const float* __restrict__ s2,
                                                     unsigned short* __restrict__ d2,
                                                     int n4){   // n4 per tensor
    int i = blockIdx.x * blockDim.x + threadIdx.x;
    int stride = gridDim.x * blockDim.x;
    for (; i < 2 * n4; i += stride){
        const float* s = (i < n4) ? s1 : s2;
        unsigned short* d = (i < n4) ? d1 : d2;
        int j = (i < n4) ? i : i - n4;
        float4 v = ((const float4*)s)[j];
        ushort4 o;
        o.x = f2bf(v.x); o.y = f2bf(v.y); o.z = f2bf(v.z); o.w = f2bf(v.w);
        ((ushort4*)d)[j] = o;
    }
}

// ------------- router: block-aggregated top-2 (8 atomics per 64 tokens) -------------
__global__ __launch_bounds__(512) void router_kernel(const float* __restrict__ x,
                                                     const float* __restrict__ Wr,
                                                     unsigned short* __restrict__ x_bf,
                                                     float* __restrict__ pair_prob,
                                                     int* __restrict__ lists,
                                                     int* __restrict__ cnt){
    __shared__ int s_ei[128];

    int tid  = threadIdx.x;
    int wv   = tid >> 6;
    int lane = tid & 63;
    int tblk = blockIdx.x * 64;

    #pragma unroll 1
    for (int i = 0; i < 8; ++i){
        int tl = wv * 8 + i;
        int t  = tblk + tl;
        const float* xr = x + (size_t)t * D_MODEL;
        float xv[8];
        #pragma unroll
        for (int c = 0; c < 8; ++c) xv[c] = xr[lane + 64*c];
        unsigned short* xb = x_bf + (size_t)t * D_MODEL;
        #pragma unroll
        for (int c = 0; c < 8; ++c) xb[lane + 64*c] = f2bf(xv[c]);
        float lg[NE];
        #pragma unroll
        for (int e = 0; e < NE; ++e){
            const float* wr = Wr + (size_t)e * D_MODEL;
            float s = 0.f;
            #pragma unroll
            for (int c = 0; c < 8; ++c) s = fmaf(xv[c], wr[lane + 64*c], s);
            #pragma unroll
            for (int off = 32; off; off >>= 1) s += __shfl_xor(s, off);
            lg[e] = s;
        }
        if (lane == 0){
            float m = lg[0];
            #pragma unroll
            for (int e = 1; e < NE; ++e) m = fmaxf(m, lg[e]);
            float sum = 0.f;
            #pragma unroll
            for (int e = 0; e < NE; ++e) sum += expf(lg[e] - m);
            int i0 = 0; float v0 = lg[0];
            #pragma unroll
            for (int e = 1; e < NE; ++e) if (lg[e] > v0){ v0 = lg[e]; i0 = e; }
            int i1 = -1; float v1 = -1e30f;
            #pragma unroll
            for (int e = 0; e < NE; ++e) if (e != i0 && lg[e] > v1){ v1 = lg[e]; i1 = e; }
            float inv = 1.f / sum;
            pair_prob[2*t]   = expf(v0 - m) * inv;
            pair_prob[2*t+1] = expf(v1 - m) * inv;
            s_ei[2*tl]     = i0;
            s_ei[2*tl + 1] = i1;
        }
    }
    __syncthreads();

    if (wv == 0){
        int e0 = s_ei[lane];
        int e1 = s_ei[64 + lane];
        unsigned long long below = (lane == 63) ? ~0ull >> 1 : (1ull << lane) - 1;
        unsigned long long m0[NE];
        int rank0 = 0, rank1 = 0, tot = 0;
        #pragma unroll
        for (int ex = 0; ex < NE; ++ex){
            m0[ex] = __ballot(e0 == ex);
            if (e0 == ex) rank0 = __popcll(m0[ex] & below);
        }
        #pragma unroll
        for (int ex = 0; ex < NE; ++ex){
            unsigned long long m1 = __ballot(e1 == ex);
            if (e1 == ex) rank1 = __popcll(m1 & below) + __popcll(m0[ex]);
            if (lane == ex) tot = __popcll(m0[ex]) + __popcll(m1);
        }
        int base_held = 0;
        if (lane < NE) base_held = atomicAdd(&cnt[lane], tot);
        int b0 = __shfl(base_held, e0);
        int b1 = __shfl(base_held, e1);
        int pairbase = blockIdx.x * 128;
        lists[e0 * T_TOK + b0 + rank0] = pairbase + lane;
        lists[e1 * T_TOK + b1 + rank1] = pairbase + 64 + lane;
    }
}

// ================= GEMMs: A via LDS, B DIRECT-TO-REGISTERS (halves LDS traffic) ==========
// Per K-step: issue B reg-loads + stage A -> vmcnt(0)+barrier -> ds_read A + MFMA -> lgkm+barrier.
// A: 128B rows, byte ^ ((row&7)<<4) swizzle (0-conflict), inverse-swizzled global src.
// B frags load as per-lane 16B vectors: wave covers 16 rows x 64 contiguous B each (L2-resident W).

// GEMM1: H[g, f] = p * GELU( Xg[128 pairs] * W1_e^T[128f] ), K=512 (8 steps)
__global__ __launch_bounds__(256, 3) void gemm1_kernel(const unsigned short* __restrict__ x_bf,
                                                       const unsigned short* __restrict__ W1bf,
                                                       const float* __restrict__ pair_prob,
                                                       const int* __restrict__ lists,
                                                       const int* __restrict__ cnt,
                                                       unsigned short* __restrict__ H){
    __shared__ __align__(16) unsigned char lds_a[16384];
    __shared__ int   s_tok[128];
    __shared__ float s_prob[128];

    int bid = blockIdx.x;
    int q = bid >> 7, r = bid & 127;
    int tg = q * 8 + (r & 7);
    int f0 = (r >> 3) << 7;
    int e = -1, tm = 0, rem = tg, pfx = 0;
    for (int i = 0; i < NE; ++i){
        int c = cnt[i];
        int mt = (c + 127) >> 7;
        if (e < 0){ if (rem < mt){ e = i; tm = rem; } else { rem -= mt; pfx += c; } }
    }
    if (e < 0) return;
    int ne = cnt[e];

    int tid = threadIdx.x;
    if (tid < 128){
        int idx = tm * 128 + tid;
        int pair = (idx < ne) ? lists[e * T_TOK + idx] : 0;
        s_tok[tid]  = (idx < ne) ? (pair >> 1) : 0;
        s_prob[tid] = (idx < ne) ? pair_prob[pair] : 0.f;
    }
    __syncthreads();

    int wv = tid >> 6, lane = tid & 63, l15 = lane & 15, lk = lane >> 4;
    int wm = wv >> 1, wn = wv & 1;

    int scol = (((lane & 7) ^ (lane >> 3)) << 3);   // inverse-swizzled source col (elements)
    const unsigned short* pa[4];
    #pragma unroll
    for (int j = 0; j < 4; ++j){
        int row = j * 32 + wv * 8 + (lane >> 3);
        pa[j] = x_bf + (size_t)s_tok[row] * D_MODEL + scol;
    }
    // B fragment pointers: row = f0 + wn*64 + nf*16 + l15, k-offset = k*64 + kk*32 + lk*8
    const unsigned short* pbB[4];
    #pragma unroll
    for (int nf = 0; nf < 4; ++nf)
        pbB[nf] = W1bf + ((size_t)e * D_FF + f0 + wn * 64 + nf * 16 + l15) * D_MODEL + lk * 8;
    int dstoff = wv * 1024;

    f32x4 zero4 = {0.f, 0.f, 0.f, 0.f};
    f32x4 acc[4][4];
    #pragma unroll
    for (int i = 0; i < 4; ++i)
        #pragma unroll
        for (int j = 0; j < 4; ++j) acc[i][j] = zero4;

    #pragma unroll 1
    for (int k = 0; k < 8; ++k){
        bf16x8 b0[4], b1[4];
        #pragma unroll
        for (int nf = 0; nf < 4; ++nf){
            b0[nf] = *(const bf16x8*)(pbB[nf] + k * 64);
            b1[nf] = *(const bf16x8*)(pbB[nf] + k * 64 + 32);
        }
        #pragma unroll
        for (int j = 0; j < 4; ++j)
            gload16(pa[j] + k * 64, lds_a + dstoff + j * 4096);
        asm volatile("s_waitcnt vmcnt(0)\n\ts_barrier" ::: "memory");
        #pragma unroll
        for (int kk = 0; kk < 2; ++kk){
            int co = (kk * 64 + lk * 16) ^ ((l15 & 7) << 4);
            bf16x8 a[4];
            #pragma unroll
            for (int mf = 0; mf < 4; ++mf)
                a[mf] = *(const bf16x8*)(lds_a + (wm * 64 + mf * 16 + l15) * 128 + co);
            #pragma unroll
            for (int mf = 0; mf < 4; ++mf)
                #pragma unroll
                for (int nf = 0; nf < 4; ++nf)
                    acc[mf][nf] = __builtin_amdgcn_mfma_f32_16x16x32_bf16(a[mf], kk ? b1[nf] : b0[nf], acc[mf][nf], 0, 0, 0);
        }
        asm volatile("s_waitcnt lgkmcnt(0)\n\ts_barrier" ::: "memory");
    }

    // epilogue: p * GELU -> bf16 -> H_k[slab][g][64], 16KB-contiguous per (tile, slab)
    {
        unsigned short* hs = H + (size_t)((f0 >> 6) + wn) * SLABU + l15;
        int gbase = pfx + tm * 128;
        #pragma unroll
        for (int mf = 0; mf < 4; ++mf){
            #pragma unroll
            for (int rr = 0; rr < 4; ++rr){
                int trow = wm * 64 + mf * 16 + lk * 4 + rr;
                if (tm * 128 + trow < ne){
                    float p = s_prob[trow];
                    unsigned short* hrow = hs + (size_t)(gbase + trow) * 64;
                    #pragma unroll
                    for (int nf = 0; nf < 4; ++nf)
                        hrow[nf * 16] = f2bf(p * gelu_f(acc[mf][nf][rr]));
                }
            }
        }
    }
}

// GEMM2: y[pair] = H[128 rows] * W2_e^T[128d], K=2048 (32 steps), NON-ATOMIC store to ybuf.
__global__ __launch_bounds__(256, 3) void gemm2_kernel(const unsigned short* __restrict__ H,
                                                       const unsigned short* __restrict__ W2bf,
                                                       const int* __restrict__ lists,
                                                       const int* __restrict__ cnt,
                                                       unsigned short* __restrict__ ybuf){
    __shared__ __align__(16) unsigned char lds_a[16384];
    __shared__ int s_pair[128];

    int bid = blockIdx.x;
    int q = bid >> 5, r = bid & 31;
    int tg = q * 8 + (r & 7);
    int d0 = (r >> 3) << 7;
    int e = -1, tm = 0, rem = tg, pfx = 0;
    for (int i = 0; i < NE; ++i){
        int c = cnt[i];
        int mt = (c + 127) >> 7;
        if (e < 0){ if (rem < mt){ e = i; tm = rem; } else { rem -= mt; pfx += c; } }
    }
    if (e < 0) return;
    int ne = cnt[e];

    int tid = threadIdx.x;
    if (tid < 128){
        int idx = tm * 128 + tid;
        s_pair[tid] = (idx < ne) ? lists[e * T_TOK + idx] : 0;
    }
    __syncthreads();

    int wv = tid >> 6, lane = tid & 63, l15 = lane & 15, lk = lane >> 4;
    int wm = wv >> 1, wn = wv & 1;

    int scol = (((lane & 7) ^ (lane >> 3)) << 3);
    const unsigned short* pa[4];
    int gbase = pfx + tm * 128;
    #pragma unroll
    for (int j = 0; j < 4; ++j){
        int row = j * 32 + wv * 8 + (lane >> 3);
        pa[j] = H + (size_t)(gbase + row) * 64 + scol;          // K-slab 0; +k*SLABU per step
    }
    const unsigned short* pbB[4];
    #pragma unroll
    for (int nf = 0; nf < 4; ++nf)
        pbB[nf] = W2bf + ((size_t)e * D_MODEL + d0 + wn * 64 + nf * 16 + l15) * D_FF + lk * 8;
    int dstoff = wv * 1024;

    f32x4 zero4 = {0.f, 0.f, 0.f, 0.f};
    f32x4 acc[4][4];
    #pragma unroll
    for (int i = 0; i < 4; ++i)
        #pragma unroll
        for (int j = 0; j < 4; ++j) acc[i][j] = zero4;

    #pragma unroll 1
    for (int k = 0; k < 32; ++k){
        bf16x8 b0[4], b1[4];
        #pragma unroll
        for (int nf = 0; nf < 4; ++nf){
            b0[nf] = *(const bf16x8*)(pbB[nf] + k * 64);
            b1[nf] = *(const bf16x8*)(pbB[nf] + k * 64 + 32);
        }
        #pragma unroll
        for (int j = 0; j < 4; ++j)
            gload16(pa[j] + (size_t)k * SLABU, lds_a + dstoff + j * 4096);
        asm volatile("s_waitcnt vmcnt(0)\n\ts_barrier" ::: "memory");
        #pragma unroll
        for (int kk = 0; kk < 2; ++kk){
            int co = (kk * 64 + lk * 16) ^ ((l15 & 7) << 4);
            bf16x8 a[4];
            #pragma unroll
            for (int mf = 0; mf < 4; ++mf)
                a[mf] = *(const bf16x8*)(lds_a + (wm * 64 + mf * 16 + l15) * 128 + co);
            #pragma unroll
            for (int mf = 0; mf < 4; ++mf)
                #pragma unroll
                for (int nf = 0; nf < 4; ++nf)
                    acc[mf][nf] = __builtin_amdgcn_mfma_f32_16x16x32_bf16(a[mf], kk ? b1[nf] : b0[nf], acc[mf][nf], 0, 0, 0);
        }
        asm volatile("s_waitcnt lgkmcnt(0)\n\ts_barrier" ::: "memory");
    }

    // epilogue: non-atomic bf16 store of y rows (p folded into H by gemm1)
    #pragma unroll
    for (int mf = 0; mf < 4; ++mf){
        #pragma unroll
        for (int rr = 0; rr < 4; ++rr){
            int trow = wm * 64 + mf * 16 + lk * 4 + rr;
            int idx  = tm * 128 + trow;
            if (idx < ne){
                unsigned short* yrow = ybuf + (size_t)s_pair[trow] * D_MODEL + d0 + wn * 64 + l15;
                #pragma unroll
                for (int nf = 0; nf < 4; ++nf)
                    yrow[nf * 16] = f2bf(acc[mf][nf][rr]);
            }
        }
    }
}

// ---------------- combine: out[t] = y[2t] + y[2t+1] (p already folded into H) ----------------
__global__ __launch_bounds__(256) void combine_kernel(const unsigned short* __restrict__ ybuf,
                                                      float* __restrict__ out){
    int gid  = blockIdx.x * 256 + threadIdx.x;
    int t    = gid >> 6;
    int lane = gid & 63;
    if (t >= T_TOK) return;
    const unsigned short* y0 = ybuf + (size_t)(2 * t) * D_MODEL + lane * 8;
    const unsigned short* y1 = y0 + D_MODEL;
    unsigned short a[8], b[8];
    *(int4*)a = *(const int4*)y0;
    *(int4*)b = *(const int4*)y1;
    float res[8];
    #pragma unroll
    for (int j = 0; j < 8; ++j) res[j] = bf2f(a[j]) + bf2f(b[j]);
    float* orow = out + (size_t)t * D_MODEL + lane * 8;
    *(float4*)(orow)     = *(float4*)(res);
    *(float4*)(orow + 4) = *(float4*)(res + 4);
}

// ================= fallback: fused kernel (used only if ws too small) =================
__global__ __launch_bounds__(512, 2) void moe_ffn_fallback(const unsigned short* __restrict__ x_bf,
                                                           const unsigned short* __restrict__ W1bf,
                                                           const unsigned short* __restrict__ W2bf,
                                                           const float* __restrict__ pair_prob,
                                                           const int* __restrict__ lists,
                                                           const int* __restrict__ cnt,
                                                           float* __restrict__ out){
    __shared__ __align__(16) unsigned char lds_x[64 * 1024];
    __shared__ __align__(16) unsigned char lds_h[64 * 256];
    int bid  = blockIdx.x;
    int xcd  = bid & 7, slot = bid >> 3;
    int eA   = xcd >> 1, sA = xcd & 1;
    int eB   = eA + 4;
    int tA   = (cnt[eA] + 63) >> 6;
    int tB   = (cnt[eB] + 63) >> 6;
    int e, sp, tile;
    if (slot < tA)           { e = eA; sp = sA; tile = slot; }
    else if (slot < tA + tB) { e = eB; sp = sA; tile = slot - tA; }
    else return;
    int ne = cnt[e];
    int tid = threadIdx.x;
    {
        int row = tid >> 3;
        int idx = tile * 64 + row;
        int tok = 0;
        if (idx < ne) tok = lists[e * T_TOK + idx] >> 1;
        int seg = (tid & 7) * 64;
        const unsigned short* src = x_bf + (size_t)tok * D_MODEL + seg;
        int sw = (row & 7) << 4;
        #pragma unroll
        for (int g = 0; g < 8; ++g){
            int4 v = *(const int4*)(src + g * 8);
            int col2 = (seg + g * 8) * 2;
            *(int4*)(lds_x + row * 1024 + (col2 ^ sw)) = v;
        }
    }
    __syncthreads();
    int wv = tid >> 6, lane = tid & 63, l15 = lane & 15, lk = lane >> 4;
    int swz = (l15 & 7) << 4;
    f32x4 zero4 = {0.f, 0.f, 0.f, 0.f};
    f32x4 yacc[4][4];
    #pragma unroll
    for (int i = 0; i < 4; ++i)
        #pragma unroll
        for (int j = 0; j < 4; ++j) yacc[i][j] = zero4;
    const unsigned short* w1p0 = W1bf + ((size_t)e * D_FF + sp * 1024 + wv * 16 + l15) * D_MODEL + lk * 8;
    const unsigned short* w2p0 = W2bf + ((size_t)e * D_MODEL + wv * 64 + l15) * D_FF + sp * 1024 + lk * 8;
    for (int fc = 0; fc < 8; ++fc){
        f32x4 hacc[4];
        #pragma unroll
        for (int at = 0; at < 4; ++at) hacc[at] = zero4;
        const unsigned short* w1p = w1p0 + (size_t)(fc * 128) * D_MODEL;
        #pragma unroll
        for (int ks = 0; ks < 16; ++ks){
            bf16x8 bb = *(const bf16x8*)(w1p + ks * 32);
            int col2 = (ks * 32 + lk * 8) * 2;
            #pragma unroll
            for (int at = 0; at < 4; ++at){
                bf16x8 a = *(const bf16x8*)(lds_x + (at * 16 + l15) * 1024 + (col2 ^ swz));
                hacc[at] = __builtin_amdgcn_mfma_f32_16x16x32_bf16(a, bb, hacc[at], 0, 0, 0);
            }
        }
        {
            int fl2 = (wv * 16 + l15) * 2;
            #pragma unroll
            for (int at = 0; at < 4; ++at){
                #pragma unroll
                for (int rr = 0; rr < 4; ++rr){
                    int tok = at * 16 + lk * 4 + rr;
                    *(unsigned short*)(lds_h + tok * 256 + (fl2 ^ ((tok & 7) << 4))) = f2bf(gelu_f(hacc[at][rr]));
                }
            }
        }
        asm volatile("s_waitcnt lgkmcnt(0)\n\ts_barrier" ::: "memory");
        const unsigned short* w2p = w2p0 + fc * 128;
        #pragma unroll
        for (int ks2 = 0; ks2 < 4; ++ks2){
            int col2 = (ks2 * 32 + lk * 8) * 2;
            bf16x8 am[4];
            #pragma unroll
            for (int mt = 0; mt < 4; ++mt)
                am[mt] = *(const bf16x8*)(lds_h + (mt * 16 + l15) * 256 + (col2 ^ swz));
            #pragma unroll
            for (int nt = 0; nt < 4; ++nt){
                bf16x8 bb = *(const bf16x8*)(w2p + (size_t)nt * 16 * D_FF + ks2 * 32);
                #pragma unroll
                for (int mt = 0; mt < 4; ++mt)
                    yacc[mt][nt] = __builtin_amdgcn_mfma_f32_16x16x32_bf16(am[mt], bb, yacc[mt][nt], 0, 0, 0);
            }
        }
        asm volatile("s_waitcnt lgkmcnt(0)\n\ts_barrier" ::: "memory");
    }
    const int* lrow = lists + e * T_TOK + tile * 64;
    #pragma unroll
    for (int mt = 0; mt < 4; ++mt){
        #pragma unroll
        for (int rr = 0; rr < 4; ++rr){
            int trow = mt * 16 + lk * 4 + rr;
            int idx  = tile * 64 + trow;
            if (idx < ne){
                int pair = lrow[trow];
                float p  = pair_prob[pair];
                float* orow = out + (size_t)(pair >> 1) * D_MODEL;
                #pragma unroll
                for (int nt = 0; nt < 4; ++nt)
                    atomicAdd(orow + wv * 64 + nt * 16 + l15, p * yacc[mt][nt][rr]);
            }
        }
    }
}

extern "C" void kernel_launch(void* const* d_in, const int* in_sizes, int n_in,
                              void* d_out, int out_size, void* d_ws, size_t ws_size,
                              hipStream_t stream){
    const float* x  = (const float*)d_in[0];
    const float* Wr = (const float*)d_in[1];
    const float* W1 = (const float*)d_in[2];
    const float* W2 = (const float*)d_in[3];
    float* out = (float*)d_out;

    char* ws = (char*)d_ws;
    unsigned short* x_bf = (unsigned short*)(ws);                  //  8,388,608
    unsigned short* W1bf = (unsigned short*)(ws + 8388608);        // 16,777,216
    unsigned short* W2bf = (unsigned short*)(ws + 25165824);       // 16,777,216
    unsigned short* H    = (unsigned short*)(ws + 41943040);       // 67,108,864 (64MB used + slack)
    float* pair_prob     = (float*)(ws + 109051904);               //     65,536
    int*   lists         = (int*)(ws + 109117440);                 //    262,144
    int*   cnt           = (int*)(ws + 109379584);                 //         32
    // ybuf (16,777,216 B bf16) aliases x_bf+W1bf — both dead after gemm1
    unsigned short* ybuf = (unsigned short*)(ws);
    const size_t NEED = 109379616;
    bool big = ws_size >= NEED;
    if (!big){
        pair_prob = (float*)(ws + 41943040);
        lists     = (int*)(ws + 42008576);
        cnt       = (int*)(ws + 42270720);
    }

    hipMemsetAsync(cnt, 0, NE * sizeof(int), stream);

    cvt2_f32_bf16<<<2048, 256, 0, stream>>>(W1, W1bf, W2, W2bf, (NE * D_FF * D_MODEL) / 4);

    router_kernel<<<T_TOK / 64, 512, 0, stream>>>(x, Wr, x_bf, pair_prob, lists, cnt);

    if (big){
        // 17 q-groups cover worst-case 136 tiles (128-pair tiles); idle tail blocks exit early
        gemm1_kernel<<<17 * 128, 256, 0, stream>>>(x_bf, W1bf, pair_prob, lists, cnt, H);
        gemm2_kernel<<<17 * 32, 256, 0, stream>>>(H, W2bf, lists, cnt, ybuf);
        combine_kernel<<<(T_TOK * 64) / 256, 256, 0, stream>>>(ybuf, out);
    } else {
        hipMemsetAsync(d_out, 0, (size_t)out_size * sizeof(float), stream);
        moe_ffn_fallback<<<2080, 512, 0, stream>>>(x_bf, W1bf, W2bf, pair_prob, lists, cnt, out);
    }
}

// Round 13
// 176.582 us; speedup vs baseline: 1.4591x; 1.4591x over previous
//
#include <hip/hip_runtime.h>
#include <hip/hip_bf16.h>
#include <math.h>

#define D_MODEL 512
#define D_FF    2048
#define NE      8
#define T_TOK   8192
#define SLABU   (16384 * 64)   // ushorts per 64-col K-slab of H

typedef __attribute__((ext_vector_type(8))) short bf16x8;
typedef __attribute__((ext_vector_type(4))) float f32x4;

static __device__ __forceinline__ unsigned short f2bf(float f){
    union { float f; unsigned u; } v; v.f = f;
    unsigned r = v.u + 0x7FFFu + ((v.u >> 16) & 1u);   // RNE
    return (unsigned short)(r >> 16);
}
static __device__ __forceinline__ float bf2f(unsigned short u){
    union { unsigned u; float f; } v; v.u = ((unsigned)u) << 16; return v.f;
}

// tanh-form GELU via exp2 (abs err <= ~3e-4, well under bf16 rounding of h)
static __device__ __forceinline__ float gelu_f(float x){
    float z = 0.7978845608028654f * (x + 0.044715f * x * x * x);
    float e = __builtin_amdgcn_exp2f(z * 2.8853900817779268f);  // e^(2z)
    float t = 1.f - 2.f * __builtin_amdgcn_rcpf(e + 1.f);       // tanh(z)
    return 0.5f * x * (1.f + t);
}

static __device__ __forceinline__ void gload16(const void* g, void* l){
    __builtin_amdgcn_global_load_lds((const __attribute__((address_space(1))) unsigned int*)g,
                                     (__attribute__((address_space(3))) unsigned int*)l, 16, 0, 0);
}

// ---------------- f32 -> bf16 conversion of BOTH weight tensors in one dispatch ----------------
__global__ __launch_bounds__(256) void cvt2_f32_bf16(const float* __restrict__ s1,
                                                     unsigned short* __restrict__ d1,
                                                     const float* __restrict__ s2,
                                                     unsigned short* __restrict__ d2,
                                                     int n4){   // n4 per tensor
    int i = blockIdx.x * blockDim.x + threadIdx.x;
    int stride = gridDim.x * blockDim.x;
    for (; i < 2 * n4; i += stride){
        const float* s = (i < n4) ? s1 : s2;
        unsigned short* d = (i < n4) ? d1 : d2;
        int j = (i < n4) ? i : i - n4;
        float4 v = ((const float4*)s)[j];
        ushort4 o;
        o.x = f2bf(v.x); o.y = f2bf(v.y); o.z = f2bf(v.z); o.w = f2bf(v.w);
        ((ushort4*)d)[j] = o;
    }
}

// ------------- router: block-aggregated top-2 (8 atomics per 64 tokens) -------------
__global__ __launch_bounds__(512) void router_kernel(const float* __restrict__ x,
                                                     const float* __restrict__ Wr,
                                                     unsigned short* __restrict__ x_bf,
                                                     float* __restrict__ pair_prob,
                                                     int* __restrict__ lists,
                                                     int* __restrict__ cnt){
    __shared__ int s_ei[128];

    int tid  = threadIdx.x;
    int wv   = tid >> 6;
    int lane = tid & 63;
    int tblk = blockIdx.x * 64;

    #pragma unroll 1
    for (int i = 0; i < 8; ++i){
        int tl = wv * 8 + i;
        int t  = tblk + tl;
        const float* xr = x + (size_t)t * D_MODEL;
        float xv[8];
        #pragma unroll
        for (int c = 0; c < 8; ++c) xv[c] = xr[lane + 64*c];
        unsigned short* xb = x_bf + (size_t)t * D_MODEL;
        #pragma unroll
        for (int c = 0; c < 8; ++c) xb[lane + 64*c] = f2bf(xv[c]);
        float lg[NE];
        #pragma unroll
        for (int e = 0; e < NE; ++e){
            const float* wr = Wr + (size_t)e * D_MODEL;
            float s = 0.f;
            #pragma unroll
            for (int c = 0; c < 8; ++c) s = fmaf(xv[c], wr[lane + 64*c], s);
            #pragma unroll
            for (int off = 32; off; off >>= 1) s += __shfl_xor(s, off);
            lg[e] = s;
        }
        if (lane == 0){
            float m = lg[0];
            #pragma unroll
            for (int e = 1; e < NE; ++e) m = fmaxf(m, lg[e]);
            float sum = 0.f;
            #pragma unroll
            for (int e = 0; e < NE; ++e) sum += expf(lg[e] - m);
            int i0 = 0; float v0 = lg[0];
            #pragma unroll
            for (int e = 1; e < NE; ++e) if (lg[e] > v0){ v0 = lg[e]; i0 = e; }
            int i1 = -1; float v1 = -1e30f;
            #pragma unroll
            for (int e = 0; e < NE; ++e) if (e != i0 && lg[e] > v1){ v1 = lg[e]; i1 = e; }
            float inv = 1.f / sum;
            pair_prob[2*t]   = expf(v0 - m) * inv;
            pair_prob[2*t+1] = expf(v1 - m) * inv;
            s_ei[2*tl]     = i0;
            s_ei[2*tl + 1] = i1;
        }
    }
    __syncthreads();

    if (wv == 0){
        int e0 = s_ei[lane];
        int e1 = s_ei[64 + lane];
        unsigned long long below = (lane == 63) ? ~0ull >> 1 : (1ull << lane) - 1;
        unsigned long long m0[NE];
        int rank0 = 0, rank1 = 0, tot = 0;
        #pragma unroll
        for (int ex = 0; ex < NE; ++ex){
            m0[ex] = __ballot(e0 == ex);
            if (e0 == ex) rank0 = __popcll(m0[ex] & below);
        }
        #pragma unroll
        for (int ex = 0; ex < NE; ++ex){
            unsigned long long m1 = __ballot(e1 == ex);
            if (e1 == ex) rank1 = __popcll(m1 & below) + __popcll(m0[ex]);
            if (lane == ex) tot = __popcll(m0[ex]) + __popcll(m1);
        }
        int base_held = 0;
        if (lane < NE) base_held = atomicAdd(&cnt[lane], tot);
        int b0 = __shfl(base_held, e0);
        int b1 = __shfl(base_held, e1);
        int pairbase = blockIdx.x * 128;
        lists[e0 * T_TOK + b0 + rank0] = pairbase + lane;
        lists[e1 * T_TOK + b1 + rank1] = pairbase + 64 + lane;
    }
}

// ================= GEMM1: 256x256 tile, 8 waves (1M x 8N), 8-phase counted-vmcnt =================
// Per K-tile (BK=64): 4 phases, each {stage 1 half-tile (2 gload_lds), [vmcnt(6)+barrier at j=0],
// ds_read A-quadrant (8 b128), 16 MFMA (setprio-wrapped), barrier}. Stage order per tile t:
// B0,B1,A0,A1 issued at phases 4t-6..4t-3 -> min overwrite gap = 2 phases (race-free at +-1 slack).
// vmcnt never drains mid-loop. LDS 130KB -> 1 block/CU, 8 waves.
__global__ __launch_bounds__(512, 2) void gemm1_kernel(const unsigned short* __restrict__ x_bf,
                                                       const unsigned short* __restrict__ W1bf,
                                                       const float* __restrict__ pair_prob,
                                                       const int* __restrict__ lists,
                                                       const int* __restrict__ cnt,
                                                       unsigned short* __restrict__ H){
    __shared__ __align__(16) unsigned char lds_a[2][32768];   // [buf][256 rows x 64 cols bf16]
    __shared__ __align__(16) unsigned char lds_b[2][32768];
    __shared__ int   s_tok[256];
    __shared__ float s_prob[256];

    int bid = blockIdx.x;
    int q = bid >> 6, r = bid & 63;
    int tg = q * 8 + (r & 7);          // tile group (e, tm), XCD-paired
    int f0 = (r >> 3) << 8;            // 256-wide f block (0..7)
    int e = -1, tm = 0, rem = tg, pfx = 0;
    for (int i = 0; i < NE; ++i){
        int c = cnt[i];
        int mt = (c + 255) >> 8;
        if (e < 0){ if (rem < mt){ e = i; tm = rem; } else { rem -= mt; pfx += c; } }
    }
    if (e < 0) return;
    int ne = cnt[e];

    int tid = threadIdx.x;
    if (tid < 256){
        int idx = tm * 256 + tid;
        int pair = (idx < ne) ? lists[e * T_TOK + idx] : 0;
        s_tok[tid]  = (idx < ne) ? (pair >> 1) : 0;
        s_prob[tid] = (idx < ne) ? pair_prob[pair] : 0.f;
    }
    __syncthreads();

    int wid = tid >> 6, lane = tid & 63, l15 = lane & 15, lk = lane >> 4;
    int wc  = wid;                      // n-wave: cols wc*32 .. wc*32+31

    // staging source pointers: 4 row-groups each for A and B
    int scol = (((tid & 7) ^ ((tid >> 3) & 7)) << 3);   // inverse-swizzled source col (elements)
    const unsigned short* pa[4];
    const unsigned short* pb[4];
    #pragma unroll
    for (int j = 0; j < 4; ++j){
        int row = j * 64 + (tid >> 3);
        pa[j] = x_bf + (size_t)s_tok[row] * D_MODEL + scol;
        pb[j] = W1bf + ((size_t)e * D_FF + f0 + row) * D_MODEL + scol;
    }

    f32x4 zero4 = {0.f, 0.f, 0.f, 0.f};
    f32x4 acc[16][2];
    #pragma unroll
    for (int i = 0; i < 16; ++i){ acc[i][0] = zero4; acc[i][1] = zero4; }
    bf16x8 bfrag[2][2];

    #define STG_A(tau, half) { \
        unsigned char* d_ = lds_a[(tau) & 1] + (half) * 16384 + wid * 1024; \
        gload16(pa[(half)*2]     + (size_t)(tau) * 64, d_); \
        gload16(pa[(half)*2 + 1] + (size_t)(tau) * 64, d_ + 8192); }
    #define STG_B(tau, half) { \
        unsigned char* d_ = lds_b[(tau) & 1] + (half) * 16384 + wid * 1024; \
        gload16(pb[(half)*2]     + (size_t)(tau) * 64, d_); \
        gload16(pb[(half)*2 + 1] + (size_t)(tau) * 64, d_ + 8192); }

    #define PHASE_BODY(J) { \
        const unsigned char* la_ = lds_a[t & 1]; \
        bf16x8 a_[4][2]; \
        _Pragma("unroll") \
        for (int fr = 0; fr < 4; ++fr) \
            _Pragma("unroll") \
            for (int kk = 0; kk < 2; ++kk) \
                a_[fr][kk] = *(const bf16x8*)(la_ + ((J)*64 + fr*16 + l15) * 128 + ((kk*64 + lk*16) ^ ((l15 & 7) << 4))); \
        __builtin_amdgcn_s_setprio(1); \
        _Pragma("unroll") \
        for (int fr = 0; fr < 4; ++fr) \
            _Pragma("unroll") \
            for (int n = 0; n < 2; ++n) \
                _Pragma("unroll") \
                for (int kk = 0; kk < 2; ++kk) \
                    acc[(J)*4 + fr][n] = __builtin_amdgcn_mfma_f32_16x16x32_bf16(a_[fr][kk], bfrag[n][kk], acc[(J)*4 + fr][n], 0, 0, 0); \
        __builtin_amdgcn_s_setprio(0); \
        asm volatile("s_barrier" ::: "memory"); }

    // prologue: tile0 fully + tile1's B halves (6 stage units, 12 loads)
    STG_B(0, 0); STG_B(0, 1); STG_A(0, 0); STG_A(0, 1); STG_B(1, 0); STG_B(1, 1);

    #pragma unroll 1
    for (int t = 0; t < 8; ++t){
        // ---- phase 0: stage A0(t+1); tile-t readiness check; B frags + A rows 0-63
        if (t + 1 < 8) STG_A(t + 1, 0);
        if (t < 7) asm volatile("s_waitcnt vmcnt(6)" ::: "memory");
        else       asm volatile("s_waitcnt vmcnt(0)" ::: "memory");
        asm volatile("s_barrier" ::: "memory");
        {
            const unsigned char* lb_ = lds_b[t & 1];
            #pragma unroll
            for (int n = 0; n < 2; ++n)
                #pragma unroll
                for (int kk = 0; kk < 2; ++kk)
                    bfrag[n][kk] = *(const bf16x8*)(lb_ + (wc*32 + n*16 + l15) * 128 + ((kk*64 + lk*16) ^ ((l15 & 7) << 4)));
        }
        PHASE_BODY(0)
        // ---- phase 1: stage A1(t+1); A rows 64-127
        if (t + 1 < 8) STG_A(t + 1, 1);
        PHASE_BODY(1)
        // ---- phase 2: stage B0(t+2); A rows 128-191
        if (t + 2 < 8) STG_B(t + 2, 0);
        PHASE_BODY(2)
        // ---- phase 3: stage B1(t+2); A rows 192-255
        if (t + 2 < 8) STG_B(t + 2, 1);
        PHASE_BODY(3)
    }
    #undef STG_A
    #undef STG_B
    #undef PHASE_BODY

    // epilogue: p * GELU -> bf16 -> H K-major slabs (16KB-contiguous per tile/slab)
    {
        int gbase = pfx + tm * 256;
        int slab  = (f0 >> 6) + (wc >> 1);
        int cbase = (wc & 1) * 32 + l15;
        #pragma unroll
        for (int fr = 0; fr < 16; ++fr){
            #pragma unroll
            for (int rr = 0; rr < 4; ++rr){
                int trow = fr * 16 + lk * 4 + rr;
                if (tm * 256 + trow < ne){
                    float p = s_prob[trow];
                    unsigned short* hrow = H + (size_t)slab * SLABU + (size_t)(gbase + trow) * 64 + cbase;
                    hrow[0]  = f2bf(p * gelu_f(acc[fr][0][rr]));
                    hrow[16] = f2bf(p * gelu_f(acc[fr][1][rr]));
                }
            }
        }
    }
}

// ================= GEMM2 (R11-proven): 128x128, BK=64, single-buffer m97 structure ============
__global__ __launch_bounds__(256, 4) void gemm2_kernel(const unsigned short* __restrict__ H,
                                                       const unsigned short* __restrict__ W2bf,
                                                       const int* __restrict__ lists,
                                                       const int* __restrict__ cnt,
                                                       unsigned short* __restrict__ ybuf){
    __shared__ __align__(16) unsigned char lds_a[16384];
    __shared__ __align__(16) unsigned char lds_b[16384];
    __shared__ int s_pair[128];

    int bid = blockIdx.x;
    int q = bid >> 5, r = bid & 31;
    int tg = q * 8 + (r & 7);
    int d0 = (r >> 3) << 7;
    int e = -1, tm = 0, rem = tg, pfx = 0;
    for (int i = 0; i < NE; ++i){
        int c = cnt[i];
        int mt = (c + 127) >> 7;
        if (e < 0){ if (rem < mt){ e = i; tm = rem; } else { rem -= mt; pfx += c; } }
    }
    if (e < 0) return;
    int ne = cnt[e];

    int tid = threadIdx.x;
    if (tid < 128){
        int idx = tm * 128 + tid;
        s_pair[tid] = (idx < ne) ? lists[e * T_TOK + idx] : 0;
    }
    __syncthreads();

    int wv = tid >> 6, lane = tid & 63, l15 = lane & 15, lk = lane >> 4;
    int wm = wv >> 1, wn = wv & 1;

    int scol = (((lane & 7) ^ (lane >> 3)) << 3);
    const unsigned short* pa[4];
    const unsigned short* pb[4];
    int gbase = pfx + tm * 128;
    #pragma unroll
    for (int j = 0; j < 4; ++j){
        int row = j * 32 + wv * 8 + (lane >> 3);
        pa[j] = H + (size_t)(gbase + row) * 64 + scol;
        pb[j] = W2bf + ((size_t)e * D_MODEL + d0 + row) * D_FF + scol;
    }
    int dstoff = wv * 1024;

    f32x4 zero4 = {0.f, 0.f, 0.f, 0.f};
    f32x4 acc[4][4];
    #pragma unroll
    for (int i = 0; i < 4; ++i)
        #pragma unroll
        for (int j = 0; j < 4; ++j) acc[i][j] = zero4;

    #pragma unroll 1
    for (int k = 0; k < 32; ++k){
        #pragma unroll
        for (int j = 0; j < 4; ++j){
            gload16(pa[j] + (size_t)k * SLABU, lds_a + dstoff + j * 4096);
            gload16(pb[j] + k * 64,            lds_b + dstoff + j * 4096);
        }
        asm volatile("s_waitcnt vmcnt(0)\n\ts_barrier" ::: "memory");
        #pragma unroll
        for (int kk = 0; kk < 2; ++kk){
            int co = (kk * 64 + lk * 16) ^ ((l15 & 7) << 4);
            bf16x8 a[4], b[4];
            #pragma unroll
            for (int mf = 0; mf < 4; ++mf)
                a[mf] = *(const bf16x8*)(lds_a + (wm * 64 + mf * 16 + l15) * 128 + co);
            #pragma unroll
            for (int nf = 0; nf < 4; ++nf)
                b[nf] = *(const bf16x8*)(lds_b + (wn * 64 + nf * 16 + l15) * 128 + co);
            #pragma unroll
            for (int mf = 0; mf < 4; ++mf)
                #pragma unroll
                for (int nf = 0; nf < 4; ++nf)
                    acc[mf][nf] = __builtin_amdgcn_mfma_f32_16x16x32_bf16(a[mf], b[nf], acc[mf][nf], 0, 0, 0);
        }
        asm volatile("s_waitcnt lgkmcnt(0)\n\ts_barrier" ::: "memory");
    }

    // epilogue: non-atomic bf16 store of y rows (p folded into H by gemm1)
    #pragma unroll
    for (int mf = 0; mf < 4; ++mf){
        #pragma unroll
        for (int rr = 0; rr < 4; ++rr){
            int trow = wm * 64 + mf * 16 + lk * 4 + rr;
            int idx  = tm * 128 + trow;
            if (idx < ne){
                unsigned short* yrow = ybuf + (size_t)s_pair[trow] * D_MODEL + d0 + wn * 64 + l15;
                #pragma unroll
                for (int nf = 0; nf < 4; ++nf)
                    yrow[nf * 16] = f2bf(acc[mf][nf][rr]);
            }
        }
    }
}

// ---------------- combine: out[t] = y[2t] + y[2t+1] (p already folded into H) ----------------
__global__ __launch_bounds__(256) void combine_kernel(const unsigned short* __restrict__ ybuf,
                                                      float* __restrict__ out){
    int gid  = blockIdx.x * 256 + threadIdx.x;
    int t    = gid >> 6;
    int lane = gid & 63;
    if (t >= T_TOK) return;
    const unsigned short* y0 = ybuf + (size_t)(2 * t) * D_MODEL + lane * 8;
    const unsigned short* y1 = y0 + D_MODEL;
    unsigned short a[8], b[8];
    *(int4*)a = *(const int4*)y0;
    *(int4*)b = *(const int4*)y1;
    float res[8];
    #pragma unroll
    for (int j = 0; j < 8; ++j) res[j] = bf2f(a[j]) + bf2f(b[j]);
    float* orow = out + (size_t)t * D_MODEL + lane * 8;
    *(float4*)(orow)     = *(float4*)(res);
    *(float4*)(orow + 4) = *(float4*)(res + 4);
}

// ================= fallback: fused kernel (used only if ws too small) =================
__global__ __launch_bounds__(512, 2) void moe_ffn_fallback(const unsigned short* __restrict__ x_bf,
                                                           const unsigned short* __restrict__ W1bf,
                                                           const unsigned short* __restrict__ W2bf,
                                                           const float* __restrict__ pair_prob,
                                                           const int* __restrict__ lists,
                                                           const int* __restrict__ cnt,
                                                           float* __restrict__ out){
    __shared__ __align__(16) unsigned char lds_x[64 * 1024];
    __shared__ __align__(16) unsigned char lds_h[64 * 256];
    int bid  = blockIdx.x;
    int xcd  = bid & 7, slot = bid >> 3;
    int eA   = xcd >> 1, sA = xcd & 1;
    int eB   = eA + 4;
    int tA   = (cnt[eA] + 63) >> 6;
    int tB   = (cnt[eB] + 63) >> 6;
    int e, sp, tile;
    if (slot < tA)           { e = eA; sp = sA; tile = slot; }
    else if (slot < tA + tB) { e = eB; sp = sA; tile = slot - tA; }
    else return;
    int ne = cnt[e];
    int tid = threadIdx.x;
    {
        int row = tid >> 3;
        int idx = tile * 64 + row;
        int tok = 0;
        if (idx < ne) tok = lists[e * T_TOK + idx] >> 1;
        int seg = (tid & 7) * 64;
        const unsigned short* src = x_bf + (size_t)tok * D_MODEL + seg;
        int sw = (row & 7) << 4;
        #pragma unroll
        for (int g = 0; g < 8; ++g){
            int4 v = *(const int4*)(src + g * 8);
            int col2 = (seg + g * 8) * 2;
            *(int4*)(lds_x + row * 1024 + (col2 ^ sw)) = v;
        }
    }
    __syncthreads();
    int wv = tid >> 6, lane = tid & 63, l15 = lane & 15, lk = lane >> 4;
    int swz = (l15 & 7) << 4;
    f32x4 zero4 = {0.f, 0.f, 0.f, 0.f};
    f32x4 yacc[4][4];
    #pragma unroll
    for (int i = 0; i < 4; ++i)
        #pragma unroll
        for (int j = 0; j < 4; ++j) yacc[i][j] = zero4;
    const unsigned short* w1p0 = W1bf + ((size_t)e * D_FF + sp * 1024 + wv * 16 + l15) * D_MODEL + lk * 8;
    const unsigned short* w2p0 = W2bf + ((size_t)e * D_MODEL + wv * 64 + l15) * D_FF + sp * 1024 + lk * 8;
    for (int fc = 0; fc < 8; ++fc){
        f32x4 hacc[4];
        #pragma unroll
        for (int at = 0; at < 4; ++at) hacc[at] = zero4;
        const unsigned short* w1p = w1p0 + (size_t)(fc * 128) * D_MODEL;
        #pragma unroll
        for (int ks = 0; ks < 16; ++ks){
            bf16x8 bb = *(const bf16x8*)(w1p + ks * 32);
            int col2 = (ks * 32 + lk * 8) * 2;
            #pragma unroll
            for (int at = 0; at < 4; ++at){
                bf16x8 a = *(const bf16x8*)(lds_x + (at * 16 + l15) * 1024 + (col2 ^ swz));
                hacc[at] = __builtin_amdgcn_mfma_f32_16x16x32_bf16(a, bb, hacc[at], 0, 0, 0);
            }
        }
        {
            int fl2 = (wv * 16 + l15) * 2;
            #pragma unroll
            for (int at = 0; at < 4; ++at){
                #pragma unroll
                for (int rr = 0; rr < 4; ++rr){
                    int tok = at * 16 + lk * 4 + rr;
                    *(unsigned short*)(lds_h + tok * 256 + (fl2 ^ ((tok & 7) << 4))) = f2bf(gelu_f(hacc[at][rr]));
                }
            }
        }
        asm volatile("s_waitcnt lgkmcnt(0)\n\ts_barrier" ::: "memory");
        const unsigned short* w2p = w2p0 + fc * 128;
        #pragma unroll
        for (int ks2 = 0; ks2 < 4; ++ks2){
            int col2 = (ks2 * 32 + lk * 8) * 2;
            bf16x8 am[4];
            #pragma unroll
            for (int mt = 0; mt < 4; ++mt)
                am[mt] = *(const bf16x8*)(lds_h + (mt * 16 + l15) * 256 + (col2 ^ swz));
            #pragma unroll
            for (int nt = 0; nt < 4; ++nt){
                bf16x8 bb = *(const bf16x8*)(w2p + (size_t)nt * 16 * D_FF + ks2 * 32);
                #pragma unroll
                for (int mt = 0; mt < 4; ++mt)
                    yacc[mt][nt] = __builtin_amdgcn_mfma_f32_16x16x32_bf16(am[mt], bb, yacc[mt][nt], 0, 0, 0);
            }
        }
        asm volatile("s_waitcnt lgkmcnt(0)\n\ts_barrier" ::: "memory");
    }
    const int* lrow = lists + e * T_TOK + tile * 64;
    #pragma unroll
    for (int mt = 0; mt < 4; ++mt){
        #pragma unroll
        for (int rr = 0; rr < 4; ++rr){
            int trow = mt * 16 + lk * 4 + rr;
            int idx  = tile * 64 + trow;
            if (idx < ne){
                int pair = lrow[trow];
                float p  = pair_prob[pair];
                float* orow = out + (size_t)(pair >> 1) * D_MODEL;
                #pragma unroll
                for (int nt = 0; nt < 4; ++nt)
                    atomicAdd(orow + wv * 64 + nt * 16 + l15, p * yacc[mt][nt][rr]);
            }
        }
    }
}

extern "C" void kernel_launch(void* const* d_in, const int* in_sizes, int n_in,
                              void* d_out, int out_size, void* d_ws, size_t ws_size,
                              hipStream_t stream){
    const float* x  = (const float*)d_in[0];
    const float* Wr = (const float*)d_in[1];
    const float* W1 = (const float*)d_in[2];
    const float* W2 = (const float*)d_in[3];
    float* out = (float*)d_out;

    char* ws = (char*)d_ws;
    unsigned short* x_bf = (unsigned short*)(ws);                  //  8,388,608
    unsigned short* W1bf = (unsigned short*)(ws + 8388608);        // 16,777,216
    unsigned short* W2bf = (unsigned short*)(ws + 25165824);       // 16,777,216
    unsigned short* H    = (unsigned short*)(ws + 41943040);       // 67,108,864 (64MB used + slack)
    float* pair_prob     = (float*)(ws + 109051904);               //     65,536
    int*   lists         = (int*)(ws + 109117440);                 //    262,144
    int*   cnt           = (int*)(ws + 109379584);                 //         32
    // ybuf (16,777,216 B bf16) aliases x_bf+W1bf — both dead after gemm1
    unsigned short* ybuf = (unsigned short*)(ws);
    const size_t NEED = 109379616;
    bool big = ws_size >= NEED;
    if (!big){
        pair_prob = (float*)(ws + 41943040);
        lists     = (int*)(ws + 42008576);
        cnt       = (int*)(ws + 42270720);
    }

    hipMemsetAsync(cnt, 0, NE * sizeof(int), stream);

    cvt2_f32_bf16<<<2048, 256, 0, stream>>>(W1, W1bf, W2, W2bf, (NE * D_FF * D_MODEL) / 4);

    router_kernel<<<T_TOK / 64, 512, 0, stream>>>(x, Wr, x_bf, pair_prob, lists, cnt);

    if (big){
        // gemm1: 9 q-groups x 8 xcd-lanes x 8 f-blocks cover worst-case 71 tiles (256-pair tiles)
        gemm1_kernel<<<9 * 64, 512, 0, stream>>>(x_bf, W1bf, pair_prob, lists, cnt, H);
        // gemm2: 17 q-groups cover worst-case 136 tiles (128-pair tiles)
        gemm2_kernel<<<17 * 32, 256, 0, stream>>>(H, W2bf, lists, cnt, ybuf);
        combine_kernel<<<(T_TOK * 64) / 256, 256, 0, stream>>>(ybuf, out);
    } else {
        hipMemsetAsync(d_out, 0, (size_t)out_size * sizeof(float), stream);
        moe_ffn_fallback<<<2080, 512, 0, stream>>>(x_bf, W1bf, W2bf, pair_prob, lists, cnt, out);
    }
}

// Round 14
// 130.389 us; speedup vs baseline: 1.9760x; 1.3543x over previous
//
#include <hip/hip_runtime.h>
#include <hip/hip_bf16.h>
#include <math.h>

#define D_MODEL 512
#define D_FF    2048
#define NE      8
#define T_TOK   8192
#define SLABU   (16384 * 64)   // ushorts per 64-col K-slab of H

typedef __attribute__((ext_vector_type(8))) short bf16x8;
typedef __attribute__((ext_vector_type(4))) float f32x4;

static __device__ __forceinline__ unsigned short f2bf(float f){
    union { float f; unsigned u; } v; v.f = f;
    unsigned r = v.u + 0x7FFFu + ((v.u >> 16) & 1u);   // RNE
    return (unsigned short)(r >> 16);
}
static __device__ __forceinline__ float bf2f(unsigned short u){
    union { unsigned u; float f; } v; v.u = ((unsigned)u) << 16; return v.f;
}

// tanh-form GELU via exp2 (abs err <= ~3e-4, well under bf16 rounding of h)
static __device__ __forceinline__ float gelu_f(float x){
    float z = 0.7978845608028654f * (x + 0.044715f * x * x * x);
    float e = __builtin_amdgcn_exp2f(z * 2.8853900817779268f);  // e^(2z)
    float t = 1.f - 2.f * __builtin_amdgcn_rcpf(e + 1.f);       // tanh(z)
    return 0.5f * x * (1.f + t);
}

static __device__ __forceinline__ void gload16(const void* g, void* l){
    __builtin_amdgcn_global_load_lds((const __attribute__((address_space(1))) unsigned int*)g,
                                     (__attribute__((address_space(3))) unsigned int*)l, 16, 0, 0);
}

// ------------- fused router + weight-cvt: blocks 0-127 route, blocks 128+ convert -------------
// Router: block-aggregated top-2 (8 atomics per 64 tokens). Cvt: grid-stride f32->bf16 of W1,W2.
// Independent work, co-scheduled -> latency-bound router hides under BW-bound cvt.
__global__ __launch_bounds__(512) void router_cvt_kernel(const float* __restrict__ x,
                                                         const float* __restrict__ Wr,
                                                         const float* __restrict__ W1,
                                                         const float* __restrict__ W2,
                                                         unsigned short* __restrict__ x_bf,
                                                         unsigned short* __restrict__ W1bf,
                                                         unsigned short* __restrict__ W2bf,
                                                         float* __restrict__ pair_prob,
                                                         int* __restrict__ lists,
                                                         int* __restrict__ cnt){
    __shared__ int s_ei[128];

    int tid  = threadIdx.x;
    int bidx = blockIdx.x;

    if (bidx >= 128){
        // ---- cvt part: both weight tensors, 4.19M float4 total
        const int n4 = (NE * D_FF * D_MODEL) / 4;
        int i = (bidx - 128) * 512 + tid;
        int stride = (gridDim.x - 128) * 512;
        for (; i < 2 * n4; i += stride){
            const float* s = (i < n4) ? W1 : W2;
            unsigned short* d = (i < n4) ? W1bf : W2bf;
            int j = (i < n4) ? i : i - n4;
            float4 v = ((const float4*)s)[j];
            ushort4 o;
            o.x = f2bf(v.x); o.y = f2bf(v.y); o.z = f2bf(v.z); o.w = f2bf(v.w);
            ((ushort4*)d)[j] = o;
        }
        return;
    }

    // ---- router part
    int wv   = tid >> 6;
    int lane = tid & 63;
    int tblk = bidx * 64;

    #pragma unroll 1
    for (int i = 0; i < 8; ++i){
        int tl = wv * 8 + i;
        int t  = tblk + tl;
        const float* xr = x + (size_t)t * D_MODEL;
        float xv[8];
        #pragma unroll
        for (int c = 0; c < 8; ++c) xv[c] = xr[lane + 64*c];
        unsigned short* xb = x_bf + (size_t)t * D_MODEL;
        #pragma unroll
        for (int c = 0; c < 8; ++c) xb[lane + 64*c] = f2bf(xv[c]);
        float lg[NE];
        #pragma unroll
        for (int e = 0; e < NE; ++e){
            const float* wr = Wr + (size_t)e * D_MODEL;
            float s = 0.f;
            #pragma unroll
            for (int c = 0; c < 8; ++c) s = fmaf(xv[c], wr[lane + 64*c], s);
            #pragma unroll
            for (int off = 32; off; off >>= 1) s += __shfl_xor(s, off);
            lg[e] = s;
        }
        if (lane == 0){
            float m = lg[0];
            #pragma unroll
            for (int e = 1; e < NE; ++e) m = fmaxf(m, lg[e]);
            float sum = 0.f;
            #pragma unroll
            for (int e = 0; e < NE; ++e) sum += expf(lg[e] - m);
            int i0 = 0; float v0 = lg[0];
            #pragma unroll
            for (int e = 1; e < NE; ++e) if (lg[e] > v0){ v0 = lg[e]; i0 = e; }
            int i1 = -1; float v1 = -1e30f;
            #pragma unroll
            for (int e = 0; e < NE; ++e) if (e != i0 && lg[e] > v1){ v1 = lg[e]; i1 = e; }
            float inv = 1.f / sum;
            pair_prob[2*t]   = expf(v0 - m) * inv;
            pair_prob[2*t+1] = expf(v1 - m) * inv;
            s_ei[2*tl]     = i0;
            s_ei[2*tl + 1] = i1;
        }
    }
    __syncthreads();

    if (wv == 0){
        int e0 = s_ei[lane];
        int e1 = s_ei[64 + lane];
        unsigned long long below = (lane == 63) ? ~0ull >> 1 : (1ull << lane) - 1;
        unsigned long long m0[NE];
        int rank0 = 0, rank1 = 0, tot = 0;
        #pragma unroll
        for (int ex = 0; ex < NE; ++ex){
            m0[ex] = __ballot(e0 == ex);
            if (e0 == ex) rank0 = __popcll(m0[ex] & below);
        }
        #pragma unroll
        for (int ex = 0; ex < NE; ++ex){
            unsigned long long m1 = __ballot(e1 == ex);
            if (e1 == ex) rank1 = __popcll(m1 & below) + __popcll(m0[ex]);
            if (lane == ex) tot = __popcll(m0[ex]) + __popcll(m1);
        }
        int base_held = 0;
        if (lane < NE) base_held = atomicAdd(&cnt[lane], tot);
        int b0 = __shfl(base_held, e0);
        int b1 = __shfl(base_held, e1);
        int pairbase = bidx * 128;
        lists[e0 * T_TOK + b0 + rank0] = pairbase + lane;
        lists[e1 * T_TOK + b1 + rank1] = pairbase + 64 + lane;
    }
}

// ================= GEMMs: m97 structure, 128x128 tile, BK=64, single-buffer =================
// H uses a K-MAJOR COMPACT layout: H_k[k][g][64] with g = pfx[e] + list position.
// Per K-step: STAGE -> vmcnt(0)+barrier -> ds_read+MFMA -> lgkm+barrier.
// 128B rows, byte ^ ((row&7)<<4) swizzle (0-conflict, verified), inverse-swizzled global src.
// LDS 33KB -> 4 blocks/CU co-residency (TLP hides the drains cross-block, m114).

// GEMM1: H[g, f] = p * GELU( Xg[128 pairs] * W1_e^T[128f] ), K=512 (8 steps)
__global__ __launch_bounds__(256, 4) void gemm1_kernel(const unsigned short* __restrict__ x_bf,
                                                       const unsigned short* __restrict__ W1bf,
                                                       const float* __restrict__ pair_prob,
                                                       const int* __restrict__ lists,
                                                       const int* __restrict__ cnt,
                                                       unsigned short* __restrict__ H){
    __shared__ __align__(16) unsigned char lds_a[16384];
    __shared__ __align__(16) unsigned char lds_b[16384];
    __shared__ int   s_tok[128];
    __shared__ float s_prob[128];

    int bid = blockIdx.x;
    int q = bid >> 7, r = bid & 127;
    int tg = q * 8 + (r & 7);
    int f0 = (r >> 3) << 7;
    int e = -1, tm = 0, rem = tg, pfx = 0;
    for (int i = 0; i < NE; ++i){
        int c = cnt[i];
        int mt = (c + 127) >> 7;
        if (e < 0){ if (rem < mt){ e = i; tm = rem; } else { rem -= mt; pfx += c; } }
    }
    if (e < 0) return;
    int ne = cnt[e];

    int tid = threadIdx.x;
    if (tid < 128){
        int idx = tm * 128 + tid;
        int pair = (idx < ne) ? lists[e * T_TOK + idx] : 0;
        s_tok[tid]  = (idx < ne) ? (pair >> 1) : 0;
        s_prob[tid] = (idx < ne) ? pair_prob[pair] : 0.f;
    }
    __syncthreads();

    int wv = tid >> 6, lane = tid & 63, l15 = lane & 15, lk = lane >> 4;
    int wm = wv >> 1, wn = wv & 1;

    int scol = (((lane & 7) ^ (lane >> 3)) << 3);   // inverse-swizzled source col (elements)
    const unsigned short* pa[4];
    const unsigned short* pb[4];
    #pragma unroll
    for (int j = 0; j < 4; ++j){
        int row = j * 32 + wv * 8 + (lane >> 3);
        pa[j] = x_bf + (size_t)s_tok[row] * D_MODEL + scol;
        pb[j] = W1bf + ((size_t)e * D_FF + f0 + row) * D_MODEL + scol;
    }
    int dstoff = wv * 1024;

    f32x4 zero4 = {0.f, 0.f, 0.f, 0.f};
    f32x4 acc[4][4];
    #pragma unroll
    for (int i = 0; i < 4; ++i)
        #pragma unroll
        for (int j = 0; j < 4; ++j) acc[i][j] = zero4;

    #pragma unroll 1
    for (int k = 0; k < 8; ++k){
        #pragma unroll
        for (int j = 0; j < 4; ++j){
            gload16(pa[j] + k * 64, lds_a + dstoff + j * 4096);
            gload16(pb[j] + k * 64, lds_b + dstoff + j * 4096);
        }
        asm volatile("s_waitcnt vmcnt(0)\n\ts_barrier" ::: "memory");
        #pragma unroll
        for (int kk = 0; kk < 2; ++kk){
            int co = (kk * 64 + lk * 16) ^ ((l15 & 7) << 4);
            bf16x8 a[4], b[4];
            #pragma unroll
            for (int mf = 0; mf < 4; ++mf)
                a[mf] = *(const bf16x8*)(lds_a + (wm * 64 + mf * 16 + l15) * 128 + co);
            #pragma unroll
            for (int nf = 0; nf < 4; ++nf)
                b[nf] = *(const bf16x8*)(lds_b + (wn * 64 + nf * 16 + l15) * 128 + co);
            #pragma unroll
            for (int mf = 0; mf < 4; ++mf)
                #pragma unroll
                for (int nf = 0; nf < 4; ++nf)
                    acc[mf][nf] = __builtin_amdgcn_mfma_f32_16x16x32_bf16(a[mf], b[nf], acc[mf][nf], 0, 0, 0);
        }
        asm volatile("s_waitcnt lgkmcnt(0)\n\ts_barrier" ::: "memory");
    }

    // epilogue: p * GELU -> bf16 -> H_k[slab][g][64], 16KB-contiguous per (tile, slab)
    {
        unsigned short* hs = H + (size_t)((f0 >> 6) + wn) * SLABU + l15;
        int gbase = pfx + tm * 128;
        #pragma unroll
        for (int mf = 0; mf < 4; ++mf){
            #pragma unroll
            for (int rr = 0; rr < 4; ++rr){
                int trow = wm * 64 + mf * 16 + lk * 4 + rr;
                if (tm * 128 + trow < ne){
                    float p = s_prob[trow];
                    unsigned short* hrow = hs + (size_t)(gbase + trow) * 64;
                    #pragma unroll
                    for (int nf = 0; nf < 4; ++nf)
                        hrow[nf * 16] = f2bf(p * gelu_f(acc[mf][nf][rr]));
                }
            }
        }
    }
}

// GEMM2: y[pair] = H[128 rows] * W2_e^T[128d], K=2048 (32 steps), NON-ATOMIC store to ybuf.
__global__ __launch_bounds__(256, 4) void gemm2_kernel(const unsigned short* __restrict__ H,
                                                       const unsigned short* __restrict__ W2bf,
                                                       const int* __restrict__ lists,
                                                       const int* __restrict__ cnt,
                                                       unsigned short* __restrict__ ybuf){
    __shared__ __align__(16) unsigned char lds_a[16384];
    __shared__ __align__(16) unsigned char lds_b[16384];
    __shared__ int s_pair[128];

    int bid = blockIdx.x;
    int q = bid >> 5, r = bid & 31;
    int tg = q * 8 + (r & 7);
    int d0 = (r >> 3) << 7;
    int e = -1, tm = 0, rem = tg, pfx = 0;
    for (int i = 0; i < NE; ++i){
        int c = cnt[i];
        int mt = (c + 127) >> 7;
        if (e < 0){ if (rem < mt){ e = i; tm = rem; } else { rem -= mt; pfx += c; } }
    }
    if (e < 0) return;
    int ne = cnt[e];

    int tid = threadIdx.x;
    if (tid < 128){
        int idx = tm * 128 + tid;
        s_pair[tid] = (idx < ne) ? lists[e * T_TOK + idx] : 0;
    }
    __syncthreads();

    int wv = tid >> 6, lane = tid & 63, l15 = lane & 15, lk = lane >> 4;
    int wm = wv >> 1, wn = wv & 1;

    int scol = (((lane & 7) ^ (lane >> 3)) << 3);
    const unsigned short* pa[4];
    const unsigned short* pb[4];
    int gbase = pfx + tm * 128;
    #pragma unroll
    for (int j = 0; j < 4; ++j){
        int row = j * 32 + wv * 8 + (lane >> 3);
        pa[j] = H + (size_t)(gbase + row) * 64 + scol;          // K-slab 0; +k*SLABU per step
        pb[j] = W2bf + ((size_t)e * D_MODEL + d0 + row) * D_FF + scol;
    }
    int dstoff = wv * 1024;

    f32x4 zero4 = {0.f, 0.f, 0.f, 0.f};
    f32x4 acc[4][4];
    #pragma unroll
    for (int i = 0; i < 4; ++i)
        #pragma unroll
        for (int j = 0; j < 4; ++j) acc[i][j] = zero4;

    #pragma unroll 1
    for (int k = 0; k < 32; ++k){
        #pragma unroll
        for (int j = 0; j < 4; ++j){
            gload16(pa[j] + (size_t)k * SLABU, lds_a + dstoff + j * 4096);
            gload16(pb[j] + k * 64,            lds_b + dstoff + j * 4096);
        }
        asm volatile("s_waitcnt vmcnt(0)\n\ts_barrier" ::: "memory");
        #pragma unroll
        for (int kk = 0; kk < 2; ++kk){
            int co = (kk * 64 + lk * 16) ^ ((l15 & 7) << 4);
            bf16x8 a[4], b[4];
            #pragma unroll
            for (int mf = 0; mf < 4; ++mf)
                a[mf] = *(const bf16x8*)(lds_a + (wm * 64 + mf * 16 + l15) * 128 + co);
            #pragma unroll
            for (int nf = 0; nf < 4; ++nf)
                b[nf] = *(const bf16x8*)(lds_b + (wn * 64 + nf * 16 + l15) * 128 + co);
            #pragma unroll
            for (int mf = 0; mf < 4; ++mf)
                #pragma unroll
                for (int nf = 0; nf < 4; ++nf)
                    acc[mf][nf] = __builtin_amdgcn_mfma_f32_16x16x32_bf16(a[mf], b[nf], acc[mf][nf], 0, 0, 0);
        }
        asm volatile("s_waitcnt lgkmcnt(0)\n\ts_barrier" ::: "memory");
    }

    // epilogue: non-atomic bf16 store of y rows (p folded into H by gemm1)
    #pragma unroll
    for (int mf = 0; mf < 4; ++mf){
        #pragma unroll
        for (int rr = 0; rr < 4; ++rr){
            int trow = wm * 64 + mf * 16 + lk * 4 + rr;
            int idx  = tm * 128 + trow;
            if (idx < ne){
                unsigned short* yrow = ybuf + (size_t)s_pair[trow] * D_MODEL + d0 + wn * 64 + l15;
                #pragma unroll
                for (int nf = 0; nf < 4; ++nf)
                    yrow[nf * 16] = f2bf(acc[mf][nf][rr]);
            }
        }
    }
}

// ---------------- combine: out[t] = y[2t] + y[2t+1] (p already folded into H) ----------------
__global__ __launch_bounds__(256) void combine_kernel(const unsigned short* __restrict__ ybuf,
                                                      float* __restrict__ out){
    int gid  = blockIdx.x * 256 + threadIdx.x;
    int t    = gid >> 6;
    int lane = gid & 63;
    if (t >= T_TOK) return;
    const unsigned short* y0 = ybuf + (size_t)(2 * t) * D_MODEL + lane * 8;
    const unsigned short* y1 = y0 + D_MODEL;
    unsigned short a[8], b[8];
    *(int4*)a = *(const int4*)y0;
    *(int4*)b = *(const int4*)y1;
    float res[8];
    #pragma unroll
    for (int j = 0; j < 8; ++j) res[j] = bf2f(a[j]) + bf2f(b[j]);
    float* orow = out + (size_t)t * D_MODEL + lane * 8;
    *(float4*)(orow)     = *(float4*)(res);
    *(float4*)(orow + 4) = *(float4*)(res + 4);
}

// ================= fallback: fused kernel (used only if ws too small) =================
__global__ __launch_bounds__(512, 2) void moe_ffn_fallback(const unsigned short* __restrict__ x_bf,
                                                           const unsigned short* __restrict__ W1bf,
                                                           const unsigned short* __restrict__ W2bf,
                                                           const float* __restrict__ pair_prob,
                                                           const int* __restrict__ lists,
                                                           const int* __restrict__ cnt,
                                                           float* __restrict__ out){
    __shared__ __align__(16) unsigned char lds_x[64 * 1024];
    __shared__ __align__(16) unsigned char lds_h[64 * 256];
    int bid  = blockIdx.x;
    int xcd  = bid & 7, slot = bid >> 3;
    int eA   = xcd >> 1, sA = xcd & 1;
    int eB   = eA + 4;
    int tA   = (cnt[eA] + 63) >> 6;
    int tB   = (cnt[eB] + 63) >> 6;
    int e, sp, tile;
    if (slot < tA)           { e = eA; sp = sA; tile = slot; }
    else if (slot < tA + tB) { e = eB; sp = sA; tile = slot - tA; }
    else return;
    int ne = cnt[e];
    int tid = threadIdx.x;
    {
        int row = tid >> 3;
        int idx = tile * 64 + row;
        int tok = 0;
        if (idx < ne) tok = lists[e * T_TOK + idx] >> 1;
        int seg = (tid & 7) * 64;
        const unsigned short* src = x_bf + (size_t)tok * D_MODEL + seg;
        int sw = (row & 7) << 4;
        #pragma unroll
        for (int g = 0; g < 8; ++g){
            int4 v = *(const int4*)(src + g * 8);
            int col2 = (seg + g * 8) * 2;
            *(int4*)(lds_x + row * 1024 + (col2 ^ sw)) = v;
        }
    }
    __syncthreads();
    int wv = tid >> 6, lane = tid & 63, l15 = lane & 15, lk = lane >> 4;
    int swz = (l15 & 7) << 4;
    f32x4 zero4 = {0.f, 0.f, 0.f, 0.f};
    f32x4 yacc[4][4];
    #pragma unroll
    for (int i = 0; i < 4; ++i)
        #pragma unroll
        for (int j = 0; j < 4; ++j) yacc[i][j] = zero4;
    const unsigned short* w1p0 = W1bf + ((size_t)e * D_FF + sp * 1024 + wv * 16 + l15) * D_MODEL + lk * 8;
    const unsigned short* w2p0 = W2bf + ((size_t)e * D_MODEL + wv * 64 + l15) * D_FF + sp * 1024 + lk * 8;
    for (int fc = 0; fc < 8; ++fc){
        f32x4 hacc[4];
        #pragma unroll
        for (int at = 0; at < 4; ++at) hacc[at] = zero4;
        const unsigned short* w1p = w1p0 + (size_t)(fc * 128) * D_MODEL;
        #pragma unroll
        for (int ks = 0; ks < 16; ++ks){
            bf16x8 bb = *(const bf16x8*)(w1p + ks * 32);
            int col2 = (ks * 32 + lk * 8) * 2;
            #pragma unroll
            for (int at = 0; at < 4; ++at){
                bf16x8 a = *(const bf16x8*)(lds_x + (at * 16 + l15) * 1024 + (col2 ^ swz));
                hacc[at] = __builtin_amdgcn_mfma_f32_16x16x32_bf16(a, bb, hacc[at], 0, 0, 0);
            }
        }
        {
            int fl2 = (wv * 16 + l15) * 2;
            #pragma unroll
            for (int at = 0; at < 4; ++at){
                #pragma unroll
                for (int rr = 0; rr < 4; ++rr){
                    int tok = at * 16 + lk * 4 + rr;
                    *(unsigned short*)(lds_h + tok * 256 + (fl2 ^ ((tok & 7) << 4))) = f2bf(gelu_f(hacc[at][rr]));
                }
            }
        }
        asm volatile("s_waitcnt lgkmcnt(0)\n\ts_barrier" ::: "memory");
        const unsigned short* w2p = w2p0 + fc * 128;
        #pragma unroll
        for (int ks2 = 0; ks2 < 4; ++ks2){
            int col2 = (ks2 * 32 + lk * 8) * 2;
            bf16x8 am[4];
            #pragma unroll
            for (int mt = 0; mt < 4; ++mt)
                am[mt] = *(const bf16x8*)(lds_h + (mt * 16 + l15) * 256 + (col2 ^ swz));
            #pragma unroll
            for (int nt = 0; nt < 4; ++nt){
                bf16x8 bb = *(const bf16x8*)(w2p + (size_t)nt * 16 * D_FF + ks2 * 32);
                #pragma unroll
                for (int mt = 0; mt < 4; ++mt)
                    yacc[mt][nt] = __builtin_amdgcn_mfma_f32_16x16x32_bf16(am[mt], bb, yacc[mt][nt], 0, 0, 0);
            }
        }
        asm volatile("s_waitcnt lgkmcnt(0)\n\ts_barrier" ::: "memory");
    }
    const int* lrow = lists + e * T_TOK + tile * 64;
    #pragma unroll
    for (int mt = 0; mt < 4; ++mt){
        #pragma unroll
        for (int rr = 0; rr < 4; ++rr){
            int trow = mt * 16 + lk * 4 + rr;
            int idx  = tile * 64 + trow;
            if (idx < ne){
                int pair = lrow[trow];
                float p  = pair_prob[pair];
                float* orow = out + (size_t)(pair >> 1) * D_MODEL;
                #pragma unroll
                for (int nt = 0; nt < 4; ++nt)
                    atomicAdd(orow + wv * 64 + nt * 16 + l15, p * yacc[mt][nt][rr]);
            }
        }
    }
}

extern "C" void kernel_launch(void* const* d_in, const int* in_sizes, int n_in,
                              void* d_out, int out_size, void* d_ws, size_t ws_size,
                              hipStream_t stream){
    const float* x  = (const float*)d_in[0];
    const float* Wr = (const float*)d_in[1];
    const float* W1 = (const float*)d_in[2];
    const float* W2 = (const float*)d_in[3];
    float* out = (float*)d_out;

    char* ws = (char*)d_ws;
    unsigned short* x_bf = (unsigned short*)(ws);                  //  8,388,608
    unsigned short* W1bf = (unsigned short*)(ws + 8388608);        // 16,777,216
    unsigned short* W2bf = (unsigned short*)(ws + 25165824);       // 16,777,216
    unsigned short* H    = (unsigned short*)(ws + 41943040);       // 67,108,864 (64MB used + slack)
    float* pair_prob     = (float*)(ws + 109051904);               //     65,536
    int*   lists         = (int*)(ws + 109117440);                 //    262,144
    int*   cnt           = (int*)(ws + 109379584);                 //         32
    // ybuf (16,777,216 B bf16) aliases x_bf+W1bf — both dead after gemm1
    unsigned short* ybuf = (unsigned short*)(ws);
    const size_t NEED = 109379616;
    bool big = ws_size >= NEED;
    if (!big){
        pair_prob = (float*)(ws + 41943040);
        lists     = (int*)(ws + 42008576);
        cnt       = (int*)(ws + 42270720);
    }

    hipMemsetAsync(cnt, 0, NE * sizeof(int), stream);

    // fused: blocks 0-127 route + emit x_bf; blocks 128-2047 convert W1,W2 to bf16
    router_cvt_kernel<<<2048, 512, 0, stream>>>(x, Wr, W1, W2, x_bf, W1bf, W2bf,
                                                pair_prob, lists, cnt);

    if (big){
        // 17 q-groups cover worst-case 136 tiles (128-pair tiles); idle tail blocks exit early
        gemm1_kernel<<<17 * 128, 256, 0, stream>>>(x_bf, W1bf, pair_prob, lists, cnt, H);
        gemm2_kernel<<<17 * 32, 256, 0, stream>>>(H, W2bf, lists, cnt, ybuf);
        combine_kernel<<<(T_TOK * 64) / 256, 256, 0, stream>>>(ybuf, out);
    } else {
        hipMemsetAsync(d_out, 0, (size_t)out_size * sizeof(float), stream);
        moe_ffn_fallback<<<2080, 512, 0, stream>>>(x_bf, W1bf, W2bf, pair_prob, lists, cnt, out);
    }
}